// Round 1
// baseline (435.179 us; speedup 1.0000x reference)
//
#include <hip/hip_runtime.h>
#include <hip/hip_bf16.h>

typedef float f32x4 __attribute__((ext_vector_type(4)));
typedef short s16x8 __attribute__((ext_vector_type(8)));
typedef unsigned short u16;

#define NH 12
#define DH 64
#define DM 768
#define S_LEN 2048
#define B_SZ 4

static __device__ __forceinline__ u16 f2bf(float f) {
  __hip_bfloat16 h = __float2bfloat16(f);
  return __builtin_bit_cast(u16, h);
}
static __device__ __forceinline__ s16x8 pack_bf16x8(float4 a, float4 b) {
  s16x8 r;
  r[0] = (short)f2bf(a.x); r[1] = (short)f2bf(a.y);
  r[2] = (short)f2bf(a.z); r[3] = (short)f2bf(a.w);
  r[4] = (short)f2bf(b.x); r[5] = (short)f2bf(b.y);
  r[6] = (short)f2bf(b.z); r[7] = (short)f2bf(b.w);
  return r;
}

// ---------------------------------------------------------------------------
// RoPE cos/sin table: tab[pos*32+i] = {cos,sin}(pos * 10000^(-2i/64)).
// ---------------------------------------------------------------------------
__global__ __launch_bounds__(256) void rope_table_kernel(float2* __restrict__ tab) {
  const int idx = blockIdx.x * 256 + threadIdx.x;   // 0..65535 exact
  const int sl = idx >> 5, i = idx & 31;
  const float inv_freq = exp2f((float)(2 * i) * (-13.287712379549449f / 64.0f));
  float s, c;
  sincosf((float)sl * inv_freq, &s, &c);
  tab[idx] = make_float2(c, s);
}

// ---------------------------------------------------------------------------
// QKV projection + RoPE. R0 change: T14-style reg prefetch of next K-step
// (loads for k0+32 issued before the compute barrier, hide under MFMAs).
// ---------------------------------------------------------------------------
#define AST 40
#define QSCALE 0.18033688011112042f   // 0.125 * log2(e)

__global__ __launch_bounds__(256) void qkv_rope_kernel(
    const float* __restrict__ x, const float* __restrict__ wq,
    const float* __restrict__ wk, const float* __restrict__ wv,
    const float2* __restrict__ tab,
    u16* __restrict__ qo, u16* __restrict__ ko, u16* __restrict__ vo)
{
  const int z = blockIdx.z;                 // 0=q 1=k 2=v
  const float* Wp = (z == 0) ? wq : (z == 1) ? wk : wv;
  u16* Op = (z == 0) ? qo : (z == 1) ? ko : vo;
  const int mTile = blockIdx.x * 64;
  const int nTile = blockIdx.y * 64;
  const int tid = threadIdx.x;
  const int wave = tid >> 6, lane = tid & 63;
  const int lm = lane & 15, lq = lane >> 4;

  __shared__ u16 Al[64 * AST];
  __shared__ u16 Wl[64 * AST];

  f32x4 acc[4];
#pragma unroll
  for (int i = 0; i < 4; ++i) acc[i] = (f32x4){0.f, 0.f, 0.f, 0.f};

  const int srow = tid >> 2, scol = (tid & 3) * 8;   // 64 rows x 32 cols

  // prefetch K-step 0
  float4 pa0, pa1, pw0, pw1;
  {
    const float* ap = &x[(size_t)(mTile + srow) * DM + scol];
    pa0 = *(const float4*)ap; pa1 = *(const float4*)(ap + 4);
    const float* wp = &Wp[(size_t)(nTile + srow) * DM + scol];
    pw0 = *(const float4*)wp; pw1 = *(const float4*)(wp + 4);
  }

  for (int k0 = 0; k0 < DM; k0 += 32) {
    __syncthreads();
    *(s16x8*)&Al[srow * AST + scol] = pack_bf16x8(pa0, pa1);
    *(s16x8*)&Wl[srow * AST + scol] = pack_bf16x8(pw0, pw1);
    if (k0 + 32 < DM) {                     // issue next K-step loads now;
      const float* ap = &x[(size_t)(mTile + srow) * DM + k0 + 32 + scol];
      pa0 = *(const float4*)ap; pa1 = *(const float4*)(ap + 4);
      const float* wp = &Wp[(size_t)(nTile + srow) * DM + k0 + 32 + scol];
      pw0 = *(const float4*)wp; pw1 = *(const float4*)(wp + 4);
    }                                       // latency hides under MFMAs below
    __syncthreads();
    s16x8 af = *(const s16x8*)&Al[(wave * 16 + lm) * AST + lq * 8];
#pragma unroll
    for (int nt = 0; nt < 4; ++nt) {
      s16x8 bf = *(const s16x8*)&Wl[(nt * 16 + lm) * AST + lq * 8];
      acc[nt] = __builtin_amdgcn_mfma_f32_16x16x32_bf16(af, bf, acc[nt], 0, 0, 0);
    }
  }

  // C/D layout (m89): col = lane&15, row = (lane>>4)*4 + r; RoPE partner in lane^1
#pragma unroll
  for (int nt = 0; nt < 4; ++nt) {
#pragma unroll
    for (int r = 0; r < 4; ++r) {
      float val = acc[nt][r];
      float partner = __shfl_xor(val, 1);
      const int mI = mTile + wave * 16 + lq * 4 + r;   // token 0..8191
      const int nI = nTile + nt * 16 + lm;             // feature 0..767
      const int b = mI >> 11, sl2 = mI & (S_LEN - 1);
      const int h = nI >> 6, dd = nI & 63;
      float res;
      if (z < 2) {
        const float2 cs = tab[sl2 * 32 + (dd >> 1)];
        res = val * cs.x + partner * ((dd & 1) ? cs.y : -cs.y);
        if (z == 0) res *= QSCALE;
        Op[(((size_t)(b * NH + h)) * S_LEN + sl2) * DH + dd] = f2bf(res);
      } else {
        // v transposed: (b,h,d,s)
        Op[(((size_t)(b * NH + h)) * DH + dd) * S_LEN + sl2] = f2bf(val);
      }
    }
  }
}

// ---------------------------------------------------------------------------
// MFMA flash attention. R0 changes:
//  (1) T14 async-STAGE: next tile's K/V global loads issued into regs right
//      after the current tile's LDS writes -> latency hides under compute.
//  (2) T13 defer-max: skip alpha-rescale of Oacc/l when the running max
//      doesn't grow by >8 (exp2 units): P <= 2^8, safe in bf16/f32. Every
//      processed tile has >=1 unmasked key per row (t*64 <= qm[g], since
//      both are =0 mod 16), so rm is always finite.
// ---------------------------------------------------------------------------
#define KVST 72
#define DEFER_THR 8.0f

__global__ __launch_bounds__(256) void attn_kernel(
    const u16* __restrict__ q, const u16* __restrict__ k,
    const u16* __restrict__ vt, u16* __restrict__ o)
{
  const int qt = (int)gridDim.x - 1 - (int)blockIdx.x;  // heavy tiles first
  const int bh = blockIdx.y;
  const size_t base = (size_t)bh * S_LEN * DH;          // same for (s,d)/(d,s)
  const int tid = threadIdx.x;
  const int wave = tid >> 6, lane = tid & 63;
  const int lm = lane & 15, lq = lane >> 4;

  __shared__ u16 Kl[64 * KVST];            // [key][d]
  __shared__ u16 Vl[64 * KVST];            // [d][key]
  __shared__ u16 Pl[4 * 32 * KVST];        // per-wave 32 q-rows x 64 keys

  const int q0 = qt * 128;
  const int qm[2] = {q0 + wave * 16, q0 + 64 + wave * 16};

  s16x8 aq[2][2];
#pragma unroll
  for (int g = 0; g < 2; ++g)
#pragma unroll
    for (int kk = 0; kk < 2; ++kk)
      aq[g][kk] = *(const s16x8*)
          &q[base + (size_t)(qm[g] + lm) * DH + kk * 32 + lq * 8];

  f32x4 Oacc[2][4];
  float m_i[2][4], l_i[2][4];
#pragma unroll
  for (int g = 0; g < 2; ++g)
#pragma unroll
    for (int i = 0; i < 4; ++i) {
      Oacc[g][i] = (f32x4){0.f, 0.f, 0.f, 0.f};
      m_i[g][i] = -1e30f; l_i[g][i] = 0.f;
    }

  const int srow = tid >> 2, scol16 = (tid & 3) * 16;
  const int ntiles = 2 * qt + 2;           // keys 0 .. q0+127

  // prefetch tile 0 into regs
  uint4 ka0, ka1, va0, va1;
  {
    const uint4* kg = (const uint4*)&k[base + (size_t)srow * DH + scol16];
    ka0 = kg[0]; ka1 = kg[1];
    const uint4* vg = (const uint4*)&vt[base + (size_t)srow * S_LEN + scol16];
    va0 = vg[0]; va1 = vg[1];
  }

  for (int t = 0; t < ntiles; ++t) {
    __syncthreads();                       // prev tile's Kl/Vl reads done
    *(uint4*)&Kl[srow * KVST + scol16] = ka0;
    *(uint4*)&Kl[srow * KVST + scol16 + 8] = ka1;
    *(uint4*)&Vl[srow * KVST + scol16] = va0;
    *(uint4*)&Vl[srow * KVST + scol16 + 8] = va1;
    if (t + 1 < ntiles) {                  // T14: issue next tile's loads NOW
      const uint4* kg = (const uint4*)
          &k[base + (size_t)((t + 1) * 64 + srow) * DH + scol16];
      ka0 = kg[0]; ka1 = kg[1];
      const uint4* vg = (const uint4*)
          &vt[base + (size_t)srow * S_LEN + (t + 1) * 64 + scol16];
      va0 = vg[0]; va1 = vg[1];
    }
    __syncthreads();

#pragma unroll
    for (int g = 0; g < 2; ++g) {
      if (t * 64 > qm[g] + 15) continue;   // fully masked (wave-uniform)

      // S = Q K^T
      f32x4 S[4];
#pragma unroll
      for (int i = 0; i < 4; ++i) S[i] = (f32x4){0.f, 0.f, 0.f, 0.f};
#pragma unroll
      for (int kk = 0; kk < 2; ++kk) {
#pragma unroll
        for (int nt = 0; nt < 4; ++nt) {
          s16x8 kf = *(const s16x8*)&Kl[(nt * 16 + lm) * KVST + kk * 32 + lq * 8];
          S[nt] = __builtin_amdgcn_mfma_f32_16x16x32_bf16(aq[g][kk], kf, S[nt], 0, 0, 0);
        }
      }

      if (t * 64 + 63 > qm[g]) {           // diagonal tile: causal mask
#pragma unroll
        for (int nt = 0; nt < 4; ++nt)
#pragma unroll
          for (int r = 0; r < 4; ++r) {
            const int keyg = t * 64 + nt * 16 + lm;
            const int qg = qm[g] + lq * 4 + r;
            if (keyg > qg) S[nt][r] = -1e30f;
          }
      }

      // online softmax (exp2 units), T13 defer-max
#pragma unroll
      for (int r = 0; r < 4; ++r) {
        float rm = fmaxf(fmaxf(S[0][r], S[1][r]), fmaxf(S[2][r], S[3][r]));
        rm = fmaxf(rm, __shfl_xor(rm, 1));
        rm = fmaxf(rm, __shfl_xor(rm, 2));
        rm = fmaxf(rm, __shfl_xor(rm, 4));
        rm = fmaxf(rm, __shfl_xor(rm, 8));
        float mn = m_i[g][r];
        if (__any(rm > mn + DEFER_THR)) {  // wave-uniform rescale branch
          const float mnew = fmaxf(mn, rm);
          const float alpha = exp2f(mn - mnew);
          l_i[g][r] *= alpha;
#pragma unroll
          for (int nt = 0; nt < 4; ++nt) Oacc[g][nt][r] *= alpha;
          m_i[g][r] = mnew;
          mn = mnew;
        }
        float rs = 0.f;
#pragma unroll
        for (int nt = 0; nt < 4; ++nt) {
          float p = exp2f(S[nt][r] - mn);
          S[nt][r] = p;
          rs += p;
        }
        rs += __shfl_xor(rs, 1);
        rs += __shfl_xor(rs, 2);
        rs += __shfl_xor(rs, 4);
        rs += __shfl_xor(rs, 8);
        l_i[g][r] += rs;
      }

      // P: C-layout regs -> per-wave LDS -> A-layout (same-wave: no barrier)
#pragma unroll
      for (int nt = 0; nt < 4; ++nt)
#pragma unroll
        for (int r = 0; r < 4; ++r)
          Pl[(wave * 32 + g * 16 + lq * 4 + r) * KVST + nt * 16 + lm] =
              f2bf(S[nt][r]);

      // O += P V
#pragma unroll
      for (int kk = 0; kk < 2; ++kk) {
        s16x8 pa = *(const s16x8*)
            &Pl[(wave * 32 + g * 16 + lm) * KVST + kk * 32 + lq * 8];
#pragma unroll
        for (int nt = 0; nt < 4; ++nt) {
          s16x8 vf = *(const s16x8*)&Vl[(nt * 16 + lm) * KVST + kk * 32 + lq * 8];
          Oacc[g][nt] = __builtin_amdgcn_mfma_f32_16x16x32_bf16(pa, vf, Oacc[g][nt], 0, 0, 0);
        }
      }
    }
  }

  // normalize + store bf16 to aw (b, s, h*64+d)
  const int b = bh / NH, h = bh % NH;
#pragma unroll
  for (int g = 0; g < 2; ++g)
#pragma unroll
    for (int nt = 0; nt < 4; ++nt)
#pragma unroll
      for (int r = 0; r < 4; ++r) {
        const int qg = qm[g] + lq * 4 + r;
        const int dd = nt * 16 + lm;
        o[((size_t)(b * S_LEN + qg)) * DM + h * DH + dd] =
            f2bf(Oacc[g][nt][r] / l_i[g][r]);
      }
}

// ---------------------------------------------------------------------------
// Out-projection GEMM: C = aw @ wo^T. R0 change: same reg prefetch.
// ---------------------------------------------------------------------------
__global__ __launch_bounds__(256) void out_proj_kernel(
    const u16* __restrict__ a, const float* __restrict__ wo,
    float* __restrict__ c)
{
  const int mTile = blockIdx.x * 64;
  const int nTile = blockIdx.y * 64;
  const int tid = threadIdx.x;
  const int wave = tid >> 6, lane = tid & 63;
  const int lm = lane & 15, lq = lane >> 4;

  __shared__ u16 Al[64 * AST];
  __shared__ u16 Wl[64 * AST];

  f32x4 acc[4];
#pragma unroll
  for (int i = 0; i < 4; ++i) acc[i] = (f32x4){0.f, 0.f, 0.f, 0.f};

  const int srow = tid >> 2, scol = (tid & 3) * 8;

  uint4 pa;
  float4 pw0, pw1;
  {
    pa = *(const uint4*)&a[(size_t)(mTile + srow) * DM + scol];
    const float* wp = &wo[(size_t)(nTile + srow) * DM + scol];
    pw0 = *(const float4*)wp; pw1 = *(const float4*)(wp + 4);
  }

  for (int k0 = 0; k0 < DM; k0 += 32) {
    __syncthreads();
    *(uint4*)&Al[srow * AST + scol] = pa;
    *(s16x8*)&Wl[srow * AST + scol] = pack_bf16x8(pw0, pw1);
    if (k0 + 32 < DM) {
      pa = *(const uint4*)&a[(size_t)(mTile + srow) * DM + k0 + 32 + scol];
      const float* wp = &wo[(size_t)(nTile + srow) * DM + k0 + 32 + scol];
      pw0 = *(const float4*)wp; pw1 = *(const float4*)(wp + 4);
    }
    __syncthreads();
    s16x8 af = *(const s16x8*)&Al[(wave * 16 + lm) * AST + lq * 8];
#pragma unroll
    for (int nt = 0; nt < 4; ++nt) {
      s16x8 bf = *(const s16x8*)&Wl[(nt * 16 + lm) * AST + lq * 8];
      acc[nt] = __builtin_amdgcn_mfma_f32_16x16x32_bf16(af, bf, acc[nt], 0, 0, 0);
    }
  }

#pragma unroll
  for (int nt = 0; nt < 4; ++nt)
#pragma unroll
    for (int r = 0; r < 4; ++r)
      c[(size_t)(mTile + wave * 16 + lq * 4 + r) * DM + nTile + nt * 16 + lm] =
          acc[nt][r];
}

// ---------------------------------------------------------------------------
extern "C" void kernel_launch(void* const* d_in, const int* in_sizes, int n_in,
                              void* d_out, int out_size, void* d_ws, size_t ws_size,
                              hipStream_t stream) {
  const float* x  = (const float*)d_in[0];   // inputs: float32
  const float* wq = (const float*)d_in[1];
  const float* wk = (const float*)d_in[2];
  const float* wv = (const float*)d_in[3];
  const float* wo = (const float*)d_in[4];
  float* out = (float*)d_out;                // output: float32
  u16* ws  = (u16*)d_ws;

  const size_t QKV = (size_t)B_SZ * S_LEN * DM;  // 6291456 elems
  u16* qw = ws;                                  // ws: 4*QKV*2 + 512KB = 50.9MB
  u16* kw = ws + QKV;
  u16* vw = ws + 2 * QKV;                        // v TRANSPOSED (b,h,d,s)
  u16* aw = ws + 3 * QKV;                        // attention out, bf16 (b,s,dm)
  float2* tab = (float2*)(ws + 4 * QKV);         // 2048 x 32 cos/sin

  rope_table_kernel<<<dim3(S_LEN * 32 / 256), 256, 0, stream>>>(tab);
  qkv_rope_kernel<<<dim3(128, 12, 3), 256, 0, stream>>>(
      x, wq, wk, wv, tab, qw, kw, vw);
  attn_kernel<<<dim3(S_LEN / 128, B_SZ * NH), 256, 0, stream>>>(qw, kw, vw, aw);
  out_proj_kernel<<<dim3(128, 12), 256, 0, stream>>>(aw, wo, out);
}

// Round 2
// 408.694 us; speedup vs baseline: 1.0648x; 1.0648x over previous
//
#include <hip/hip_runtime.h>
#include <hip/hip_bf16.h>

typedef float f32x4 __attribute__((ext_vector_type(4)));
typedef short s16x8 __attribute__((ext_vector_type(8)));
typedef unsigned short u16;

#define NH 12
#define DH 64
#define DM 768
#define S_LEN 2048
#define B_SZ 4

static __device__ __forceinline__ u16 f2bf(float f) {
  __hip_bfloat16 h = __float2bfloat16(f);
  return __builtin_bit_cast(u16, h);
}
static __device__ __forceinline__ s16x8 pack_bf16x8(float4 a, float4 b) {
  s16x8 r;
  r[0] = (short)f2bf(a.x); r[1] = (short)f2bf(a.y);
  r[2] = (short)f2bf(a.z); r[3] = (short)f2bf(a.w);
  r[4] = (short)f2bf(b.x); r[5] = (short)f2bf(b.y);
  r[6] = (short)f2bf(b.z); r[7] = (short)f2bf(b.w);
  return r;
}

// ---------------------------------------------------------------------------
// RoPE cos/sin table: tab[pos*32+i] = {cos,sin}(pos * 10000^(-2i/64)).
// ---------------------------------------------------------------------------
__global__ __launch_bounds__(256) void rope_table_kernel(float2* __restrict__ tab) {
  const int idx = blockIdx.x * 256 + threadIdx.x;   // 0..65535 exact
  const int sl = idx >> 5, i = idx & 31;
  const float inv_freq = exp2f((float)(2 * i) * (-13.287712379549449f / 64.0f));
  float s, c;
  sincosf((float)sl * inv_freq, &s, &c);
  tab[idx] = make_float2(c, s);
}

// ---------------------------------------------------------------------------
// QKV projection + RoPE. R1: BK=64 (halves barrier count), reg prefetch kept.
// ---------------------------------------------------------------------------
#define AST2 72
#define QSCALE 0.18033688011112042f   // 0.125 * log2(e)

__global__ __launch_bounds__(256) void qkv_rope_kernel(
    const float* __restrict__ x, const float* __restrict__ wq,
    const float* __restrict__ wk, const float* __restrict__ wv,
    const float2* __restrict__ tab,
    u16* __restrict__ qo, u16* __restrict__ ko, u16* __restrict__ vo)
{
  const int z = blockIdx.z;                 // 0=q 1=k 2=v
  const float* Wp = (z == 0) ? wq : (z == 1) ? wk : wv;
  u16* Op = (z == 0) ? qo : (z == 1) ? ko : vo;
  const int mTile = blockIdx.x * 64;
  const int nTile = blockIdx.y * 64;
  const int tid = threadIdx.x;
  const int wave = tid >> 6, lane = tid & 63;
  const int lm = lane & 15, lq = lane >> 4;

  __shared__ u16 Al[64 * AST2];
  __shared__ u16 Wl[64 * AST2];

  f32x4 acc[4];
#pragma unroll
  for (int i = 0; i < 4; ++i) acc[i] = (f32x4){0.f, 0.f, 0.f, 0.f};

  const int srow = tid >> 2, scol = (tid & 3) * 16;  // 64 rows x 64 cols

  // prefetch K-step 0 (16 f32 per thread per matrix)
  float4 pa0, pa1, pa2, pa3, pw0, pw1, pw2, pw3;
  {
    const float4* ap = (const float4*)&x[(size_t)(mTile + srow) * DM + scol];
    pa0 = ap[0]; pa1 = ap[1]; pa2 = ap[2]; pa3 = ap[3];
    const float4* wp = (const float4*)&Wp[(size_t)(nTile + srow) * DM + scol];
    pw0 = wp[0]; pw1 = wp[1]; pw2 = wp[2]; pw3 = wp[3];
  }

  for (int k0 = 0; k0 < DM; k0 += 64) {
    __syncthreads();
    *(s16x8*)&Al[srow * AST2 + scol]     = pack_bf16x8(pa0, pa1);
    *(s16x8*)&Al[srow * AST2 + scol + 8] = pack_bf16x8(pa2, pa3);
    *(s16x8*)&Wl[srow * AST2 + scol]     = pack_bf16x8(pw0, pw1);
    *(s16x8*)&Wl[srow * AST2 + scol + 8] = pack_bf16x8(pw2, pw3);
    if (k0 + 64 < DM) {                  // issue next K-step loads now
      const float4* ap = (const float4*)&x[(size_t)(mTile + srow) * DM + k0 + 64 + scol];
      pa0 = ap[0]; pa1 = ap[1]; pa2 = ap[2]; pa3 = ap[3];
      const float4* wp = (const float4*)&Wp[(size_t)(nTile + srow) * DM + k0 + 64 + scol];
      pw0 = wp[0]; pw1 = wp[1]; pw2 = wp[2]; pw3 = wp[3];
    }
    __syncthreads();
#pragma unroll
    for (int kk = 0; kk < 2; ++kk) {
      s16x8 af = *(const s16x8*)&Al[(wave * 16 + lm) * AST2 + kk * 32 + lq * 8];
#pragma unroll
      for (int nt = 0; nt < 4; ++nt) {
        s16x8 bf = *(const s16x8*)&Wl[(nt * 16 + lm) * AST2 + kk * 32 + lq * 8];
        acc[nt] = __builtin_amdgcn_mfma_f32_16x16x32_bf16(af, bf, acc[nt], 0, 0, 0);
      }
    }
  }

  // C/D layout (m89): col = lane&15, row = (lane>>4)*4 + r; RoPE partner in lane^1
#pragma unroll
  for (int nt = 0; nt < 4; ++nt) {
#pragma unroll
    for (int r = 0; r < 4; ++r) {
      float val = acc[nt][r];
      float partner = __shfl_xor(val, 1);
      const int mI = mTile + wave * 16 + lq * 4 + r;   // token 0..8191
      const int nI = nTile + nt * 16 + lm;             // feature 0..767
      const int b = mI >> 11, sl2 = mI & (S_LEN - 1);
      const int h = nI >> 6, dd = nI & 63;
      float res;
      if (z < 2) {
        const float2 cs = tab[sl2 * 32 + (dd >> 1)];
        res = val * cs.x + partner * ((dd & 1) ? cs.y : -cs.y);
        if (z == 0) res *= QSCALE;
        Op[(((size_t)(b * NH + h)) * S_LEN + sl2) * DH + dd] = f2bf(res);
      } else {
        // v transposed: (b,h,d,s)
        Op[(((size_t)(b * NH + h)) * DH + dd) * S_LEN + sl2] = f2bf(val);
      }
    }
  }
}

// ---------------------------------------------------------------------------
// MFMA flash attention. R1 restructure for occupancy/balance:
//  - Q-tile 64 (was 128): grid 32x48 = 1536 blocks, heavy-first. Each of the
//    4 waves owns ONE 16-row m-group. LDS 28.2KB -> 5 blocks/CU resident,
//    ~20 waves/CU sustained (was 768 unbalanced blocks decaying to a tail).
//  - Pl stride 76 u16 (was 72): P-store rows 4 apart now land 24*lq banks
//    apart -> (lq, lm>>1) covers all 32 banks -> conflict-free ds_write_b16
//    (was 4-way, ~7.3M conflict cycles/dispatch).
//  - T14 reg prefetch of next K/V tile and T13 defer-max kept from R0.
// ---------------------------------------------------------------------------
#define KVST 72
#define PST 76
#define DEFER_THR 8.0f

__global__ __launch_bounds__(256) void attn_kernel(
    const u16* __restrict__ q, const u16* __restrict__ k,
    const u16* __restrict__ vt, u16* __restrict__ o)
{
  const int j = (int)gridDim.x - 1 - (int)blockIdx.x;   // heavy tiles first
  const int bh = blockIdx.y;
  const size_t base = (size_t)bh * S_LEN * DH;          // same for (s,d)/(d,s)
  const int tid = threadIdx.x;
  const int wave = tid >> 6, lane = tid & 63;
  const int lm = lane & 15, lq = lane >> 4;

  __shared__ u16 Kl[64 * KVST];            // [key][d]
  __shared__ u16 Vl[64 * KVST];            // [d][key]
  __shared__ u16 Pl[64 * PST];             // per-wave 16 q-rows x 64 keys

  const int q0 = j * 64;
  const int qm = q0 + wave * 16;           // this wave's 16 q-rows

  s16x8 aq[2];
#pragma unroll
  for (int kk = 0; kk < 2; ++kk)
    aq[kk] = *(const s16x8*)&q[base + (size_t)(qm + lm) * DH + kk * 32 + lq * 8];

  f32x4 Oacc[4];
  float m_i[4], l_i[4];
#pragma unroll
  for (int i = 0; i < 4; ++i) {
    Oacc[i] = (f32x4){0.f, 0.f, 0.f, 0.f};
    m_i[i] = -1e30f; l_i[i] = 0.f;
  }

  const int srow = tid >> 2, scol16 = (tid & 3) * 16;
  const int ntiles = j + 1;                // keys 0 .. q0+63

  // prefetch tile 0 into regs
  uint4 ka0, ka1, va0, va1;
  {
    const uint4* kg = (const uint4*)&k[base + (size_t)srow * DH + scol16];
    ka0 = kg[0]; ka1 = kg[1];
    const uint4* vg = (const uint4*)&vt[base + (size_t)srow * S_LEN + scol16];
    va0 = vg[0]; va1 = vg[1];
  }

  for (int t = 0; t < ntiles; ++t) {
    __syncthreads();                       // prev tile's Kl/Vl reads done
    *(uint4*)&Kl[srow * KVST + scol16] = ka0;
    *(uint4*)&Kl[srow * KVST + scol16 + 8] = ka1;
    *(uint4*)&Vl[srow * KVST + scol16] = va0;
    *(uint4*)&Vl[srow * KVST + scol16 + 8] = va1;
    if (t + 1 < ntiles) {                  // T14: issue next tile's loads NOW
      const uint4* kg = (const uint4*)
          &k[base + (size_t)((t + 1) * 64 + srow) * DH + scol16];
      ka0 = kg[0]; ka1 = kg[1];
      const uint4* vg = (const uint4*)
          &vt[base + (size_t)srow * S_LEN + (t + 1) * 64 + scol16];
      va0 = vg[0]; va1 = vg[1];
    }
    __syncthreads();

    // S = Q K^T   (t*64 <= q0 <= qm, so every tile is at least partly live)
    f32x4 S[4];
#pragma unroll
    for (int i = 0; i < 4; ++i) S[i] = (f32x4){0.f, 0.f, 0.f, 0.f};
#pragma unroll
    for (int kk = 0; kk < 2; ++kk) {
#pragma unroll
      for (int nt = 0; nt < 4; ++nt) {
        s16x8 kf = *(const s16x8*)&Kl[(nt * 16 + lm) * KVST + kk * 32 + lq * 8];
        S[nt] = __builtin_amdgcn_mfma_f32_16x16x32_bf16(aq[kk], kf, S[nt], 0, 0, 0);
      }
    }

    if (t * 64 + 63 > qm) {                // diagonal tile: causal mask
#pragma unroll
      for (int nt = 0; nt < 4; ++nt)
#pragma unroll
        for (int r = 0; r < 4; ++r) {
          const int keyg = t * 64 + nt * 16 + lm;
          const int qg = qm + lq * 4 + r;
          if (keyg > qg) S[nt][r] = -1e30f;
        }
    }

    // online softmax (exp2 units), T13 defer-max
#pragma unroll
    for (int r = 0; r < 4; ++r) {
      float rm = fmaxf(fmaxf(S[0][r], S[1][r]), fmaxf(S[2][r], S[3][r]));
      rm = fmaxf(rm, __shfl_xor(rm, 1));
      rm = fmaxf(rm, __shfl_xor(rm, 2));
      rm = fmaxf(rm, __shfl_xor(rm, 4));
      rm = fmaxf(rm, __shfl_xor(rm, 8));
      float mn = m_i[r];
      if (__any(rm > mn + DEFER_THR)) {    // wave-uniform rescale branch
        const float mnew = fmaxf(mn, rm);
        const float alpha = exp2f(mn - mnew);
        l_i[r] *= alpha;
#pragma unroll
        for (int nt = 0; nt < 4; ++nt) Oacc[nt][r] *= alpha;
        m_i[r] = mnew;
        mn = mnew;
      }
      float rs = 0.f;
#pragma unroll
      for (int nt = 0; nt < 4; ++nt) {
        float p = exp2f(S[nt][r] - mn);
        S[nt][r] = p;
        rs += p;
      }
      rs += __shfl_xor(rs, 1);
      rs += __shfl_xor(rs, 2);
      rs += __shfl_xor(rs, 4);
      rs += __shfl_xor(rs, 8);
      l_i[r] += rs;
    }

    // P: C-layout regs -> per-wave LDS -> A-layout (same-wave: no barrier)
#pragma unroll
    for (int nt = 0; nt < 4; ++nt)
#pragma unroll
      for (int r = 0; r < 4; ++r)
        Pl[(wave * 16 + lq * 4 + r) * PST + nt * 16 + lm] = f2bf(S[nt][r]);

    // O += P V
#pragma unroll
    for (int kk = 0; kk < 2; ++kk) {
      s16x8 pa = *(const s16x8*)&Pl[(wave * 16 + lm) * PST + kk * 32 + lq * 8];
#pragma unroll
      for (int nt = 0; nt < 4; ++nt) {
        s16x8 vf = *(const s16x8*)&Vl[(nt * 16 + lm) * KVST + kk * 32 + lq * 8];
        Oacc[nt] = __builtin_amdgcn_mfma_f32_16x16x32_bf16(pa, vf, Oacc[nt], 0, 0, 0);
      }
    }
  }

  // normalize + store bf16 to aw (b, s, h*64+d)
  const int b = bh / NH, h = bh % NH;
#pragma unroll
  for (int nt = 0; nt < 4; ++nt)
#pragma unroll
    for (int r = 0; r < 4; ++r) {
      const int qg = qm + lq * 4 + r;
      const int dd = nt * 16 + lm;
      o[((size_t)(b * S_LEN + qg)) * DM + h * DH + dd] =
          f2bf(Oacc[nt][r] / l_i[r]);
    }
}

// ---------------------------------------------------------------------------
// Out-projection GEMM: C = aw @ wo^T. R1: BK=64, reg prefetch kept.
// ---------------------------------------------------------------------------
__global__ __launch_bounds__(256) void out_proj_kernel(
    const u16* __restrict__ a, const float* __restrict__ wo,
    float* __restrict__ c)
{
  const int mTile = blockIdx.x * 64;
  const int nTile = blockIdx.y * 64;
  const int tid = threadIdx.x;
  const int wave = tid >> 6, lane = tid & 63;
  const int lm = lane & 15, lq = lane >> 4;

  __shared__ u16 Al[64 * AST2];
  __shared__ u16 Wl[64 * AST2];

  f32x4 acc[4];
#pragma unroll
  for (int i = 0; i < 4; ++i) acc[i] = (f32x4){0.f, 0.f, 0.f, 0.f};

  const int srow = tid >> 2, scol = (tid & 3) * 16;

  uint4 pa0, pa1;
  float4 pw0, pw1, pw2, pw3;
  {
    const uint4* ap = (const uint4*)&a[(size_t)(mTile + srow) * DM + scol];
    pa0 = ap[0]; pa1 = ap[1];
    const float4* wp = (const float4*)&wo[(size_t)(nTile + srow) * DM + scol];
    pw0 = wp[0]; pw1 = wp[1]; pw2 = wp[2]; pw3 = wp[3];
  }

  for (int k0 = 0; k0 < DM; k0 += 64) {
    __syncthreads();
    *(uint4*)&Al[srow * AST2 + scol] = pa0;
    *(uint4*)&Al[srow * AST2 + scol + 8] = pa1;
    *(s16x8*)&Wl[srow * AST2 + scol]     = pack_bf16x8(pw0, pw1);
    *(s16x8*)&Wl[srow * AST2 + scol + 8] = pack_bf16x8(pw2, pw3);
    if (k0 + 64 < DM) {
      const uint4* ap = (const uint4*)&a[(size_t)(mTile + srow) * DM + k0 + 64 + scol];
      pa0 = ap[0]; pa1 = ap[1];
      const float4* wp = (const float4*)&wo[(size_t)(nTile + srow) * DM + k0 + 64 + scol];
      pw0 = wp[0]; pw1 = wp[1]; pw2 = wp[2]; pw3 = wp[3];
    }
    __syncthreads();
#pragma unroll
    for (int kk = 0; kk < 2; ++kk) {
      s16x8 af = *(const s16x8*)&Al[(wave * 16 + lm) * AST2 + kk * 32 + lq * 8];
#pragma unroll
      for (int nt = 0; nt < 4; ++nt) {
        s16x8 bf = *(const s16x8*)&Wl[(nt * 16 + lm) * AST2 + kk * 32 + lq * 8];
        acc[nt] = __builtin_amdgcn_mfma_f32_16x16x32_bf16(af, bf, acc[nt], 0, 0, 0);
      }
    }
  }

#pragma unroll
  for (int nt = 0; nt < 4; ++nt)
#pragma unroll
    for (int r = 0; r < 4; ++r)
      c[(size_t)(mTile + wave * 16 + lq * 4 + r) * DM + nTile + nt * 16 + lm] =
          acc[nt][r];
}

// ---------------------------------------------------------------------------
extern "C" void kernel_launch(void* const* d_in, const int* in_sizes, int n_in,
                              void* d_out, int out_size, void* d_ws, size_t ws_size,
                              hipStream_t stream) {
  const float* x  = (const float*)d_in[0];   // inputs: float32
  const float* wq = (const float*)d_in[1];
  const float* wk = (const float*)d_in[2];
  const float* wv = (const float*)d_in[3];
  const float* wo = (const float*)d_in[4];
  float* out = (float*)d_out;                // output: float32
  u16* ws  = (u16*)d_ws;

  const size_t QKV = (size_t)B_SZ * S_LEN * DM;  // 6291456 elems
  u16* qw = ws;                                  // ws: 4*QKV*2 + 512KB = 50.9MB
  u16* kw = ws + QKV;
  u16* vw = ws + 2 * QKV;                        // v TRANSPOSED (b,h,d,s)
  u16* aw = ws + 3 * QKV;                        // attention out, bf16 (b,s,dm)
  float2* tab = (float2*)(ws + 4 * QKV);         // 2048 x 32 cos/sin

  rope_table_kernel<<<dim3(S_LEN * 32 / 256), 256, 0, stream>>>(tab);
  qkv_rope_kernel<<<dim3(128, 12, 3), 256, 0, stream>>>(
      x, wq, wk, wv, tab, qw, kw, vw);
  attn_kernel<<<dim3(S_LEN / 64, B_SZ * NH), 256, 0, stream>>>(qw, kw, vw, aw);
  out_proj_kernel<<<dim3(128, 12), 256, 0, stream>>>(aw, wo, out);
}

// Round 3
// 306.976 us; speedup vs baseline: 1.4176x; 1.3314x over previous
//
#include <hip/hip_runtime.h>
#include <hip/hip_bf16.h>

typedef float f32x4 __attribute__((ext_vector_type(4)));
typedef short s16x8 __attribute__((ext_vector_type(8)));
typedef unsigned short u16;

#define NH 12
#define DH 64
#define DM 768
#define S_LEN 2048
#define B_SZ 4

static __device__ __forceinline__ u16 f2bf(float f) {
  __hip_bfloat16 h = __float2bfloat16(f);
  return __builtin_bit_cast(u16, h);
}
static __device__ __forceinline__ s16x8 pack_bf16x8(float4 a, float4 b) {
  s16x8 r;
  r[0] = (short)f2bf(a.x); r[1] = (short)f2bf(a.y);
  r[2] = (short)f2bf(a.z); r[3] = (short)f2bf(a.w);
  r[4] = (short)f2bf(b.x); r[5] = (short)f2bf(b.y);
  r[6] = (short)f2bf(b.z); r[7] = (short)f2bf(b.w);
  return r;
}

// ---------------------------------------------------------------------------
// RoPE cos/sin table: tab[pos*32+i] = {cos,sin}(pos * 10000^(-2i/64)).
// ---------------------------------------------------------------------------
__global__ __launch_bounds__(256) void rope_table_kernel(float2* __restrict__ tab) {
  const int idx = blockIdx.x * 256 + threadIdx.x;   // 0..65535 exact
  const int sl = idx >> 5, i = idx & 31;
  const float inv_freq = exp2f((float)(2 * i) * (-13.287712379549449f / 64.0f));
  float s, c;
  sincosf((float)sl * inv_freq, &s, &c);
  tab[idx] = make_float2(c, s);
}

// ---------------------------------------------------------------------------
// QKV projection + RoPE. R2: 128x128 tile (m93 structure), BK=32, 4 waves in
// 2x2, 4x4 16x16 fragments per wave. Reg prefetch of next K-step kept.
// ---------------------------------------------------------------------------
#define QST 40
#define QSCALE 0.18033688011112042f   // 0.125 * log2(e)

__global__ __launch_bounds__(256) void qkv_rope_kernel(
    const float* __restrict__ x, const float* __restrict__ wq,
    const float* __restrict__ wk, const float* __restrict__ wv,
    const float2* __restrict__ tab,
    u16* __restrict__ qo, u16* __restrict__ ko, u16* __restrict__ vo)
{
  const int z = blockIdx.z;                 // 0=q 1=k 2=v
  const float* Wp = (z == 0) ? wq : (z == 1) ? wk : wv;
  u16* Op = (z == 0) ? qo : (z == 1) ? ko : vo;
  const int mTile = blockIdx.x * 128;
  const int nTile = blockIdx.y * 128;
  const int tid = threadIdx.x;
  const int wave = tid >> 6, lane = tid & 63;
  const int lm = lane & 15, lq = lane >> 4;
  const int wr = wave >> 1, wc = wave & 1;  // 2x2 wave grid over 128x128

  __shared__ u16 Al[128 * QST];
  __shared__ u16 Wl[128 * QST];

  f32x4 acc[4][4];
#pragma unroll
  for (int i = 0; i < 4; ++i)
#pragma unroll
    for (int jn = 0; jn < 4; ++jn) acc[i][jn] = (f32x4){0.f, 0.f, 0.f, 0.f};

  const int srow = tid >> 1, scol = (tid & 1) * 16;  // 128 rows x 32 cols

  // prefetch K-step 0 (16 f32 per thread per matrix)
  float4 pa0, pa1, pa2, pa3, pw0, pw1, pw2, pw3;
  {
    const float4* ap = (const float4*)&x[(size_t)(mTile + srow) * DM + scol];
    pa0 = ap[0]; pa1 = ap[1]; pa2 = ap[2]; pa3 = ap[3];
    const float4* wp = (const float4*)&Wp[(size_t)(nTile + srow) * DM + scol];
    pw0 = wp[0]; pw1 = wp[1]; pw2 = wp[2]; pw3 = wp[3];
  }

  for (int k0 = 0; k0 < DM; k0 += 32) {
    __syncthreads();
    *(s16x8*)&Al[srow * QST + scol]     = pack_bf16x8(pa0, pa1);
    *(s16x8*)&Al[srow * QST + scol + 8] = pack_bf16x8(pa2, pa3);
    *(s16x8*)&Wl[srow * QST + scol]     = pack_bf16x8(pw0, pw1);
    *(s16x8*)&Wl[srow * QST + scol + 8] = pack_bf16x8(pw2, pw3);
    if (k0 + 32 < DM) {                  // issue next K-step loads now
      const float4* ap = (const float4*)&x[(size_t)(mTile + srow) * DM + k0 + 32 + scol];
      pa0 = ap[0]; pa1 = ap[1]; pa2 = ap[2]; pa3 = ap[3];
      const float4* wp = (const float4*)&Wp[(size_t)(nTile + srow) * DM + k0 + 32 + scol];
      pw0 = wp[0]; pw1 = wp[1]; pw2 = wp[2]; pw3 = wp[3];
    }
    __syncthreads();
    s16x8 af[4], bf[4];
#pragma unroll
    for (int mt = 0; mt < 4; ++mt)
      af[mt] = *(const s16x8*)&Al[(wr * 64 + mt * 16 + lm) * QST + lq * 8];
#pragma unroll
    for (int nt = 0; nt < 4; ++nt)
      bf[nt] = *(const s16x8*)&Wl[(wc * 64 + nt * 16 + lm) * QST + lq * 8];
#pragma unroll
    for (int mt = 0; mt < 4; ++mt)
#pragma unroll
      for (int nt = 0; nt < 4; ++nt)
        acc[mt][nt] = __builtin_amdgcn_mfma_f32_16x16x32_bf16(af[mt], bf[nt], acc[mt][nt], 0, 0, 0);
  }

  // C/D layout (m89): col = lane&15, row = (lane>>4)*4 + r; RoPE partner in lane^1
#pragma unroll
  for (int mt = 0; mt < 4; ++mt)
#pragma unroll
    for (int nt = 0; nt < 4; ++nt)
#pragma unroll
      for (int r = 0; r < 4; ++r) {
        float val = acc[mt][nt][r];
        float partner = __shfl_xor(val, 1);
        const int mI = mTile + wr * 64 + mt * 16 + lq * 4 + r;  // token 0..8191
        const int nI = nTile + wc * 64 + nt * 16 + lm;          // feature 0..767
        const int b = mI >> 11, sl2 = mI & (S_LEN - 1);
        const int h = nI >> 6, dd = nI & 63;
        float res;
        if (z < 2) {
          const float2 cs = tab[sl2 * 32 + (dd >> 1)];
          res = val * cs.x + partner * ((dd & 1) ? cs.y : -cs.y);
          if (z == 0) res *= QSCALE;
          Op[(((size_t)(b * NH + h)) * S_LEN + sl2) * DH + dd] = f2bf(res);
        } else {
          // v transposed: (b,h,d,s)
          Op[(((size_t)(b * NH + h)) * DH + dd) * S_LEN + sl2] = f2bf(val);
        }
      }
}

// ---------------------------------------------------------------------------
// MFMA flash attention. R2 changes:
//  - T1 XCD grouping: 1D grid p; bh = p%48, j = 31 - p/48. 48 = 0 mod 8, so
//    all 32 blocks of one bh land on XCD p%8; per-XCD K/V working set =
//    6 heads x 512KB = 3MB < 4MB L2 (was: scattered, 4x HBM re-fetch).
//    Heavy-first preserved (j descending in dispatch order).
//  - 2-deep K/V register prefetch (explicit A/B sets, static indexing):
//    loads fly ~2 tile-times ahead, covering HBM-miss latency.
//  - T13 defer-max, Pl stride 76, Q-tile 64 kept from R1.
// ---------------------------------------------------------------------------
#define KVST 72
#define PST 76
#define DEFER_THR 8.0f

__global__ __launch_bounds__(256) void attn_kernel(
    const u16* __restrict__ q, const u16* __restrict__ k,
    const u16* __restrict__ vt, u16* __restrict__ o)
{
  const int p = blockIdx.x;
  const int bh = p % 48;
  const int j = (S_LEN / 64 - 1) - p / 48;              // heavy tiles first
  const size_t base = (size_t)bh * S_LEN * DH;          // same for (s,d)/(d,s)
  const int tid = threadIdx.x;
  const int wave = tid >> 6, lane = tid & 63;
  const int lm = lane & 15, lq = lane >> 4;

  __shared__ u16 Kl[64 * KVST];            // [key][d]
  __shared__ u16 Vl[64 * KVST];            // [d][key]
  __shared__ u16 Pl[64 * PST];             // per-wave 16 q-rows x 64 keys

  const int q0 = j * 64;
  const int qm = q0 + wave * 16;           // this wave's 16 q-rows

  s16x8 aq[2];
#pragma unroll
  for (int kk = 0; kk < 2; ++kk)
    aq[kk] = *(const s16x8*)&q[base + (size_t)(qm + lm) * DH + kk * 32 + lq * 8];

  f32x4 Oacc[4];
  float m_i[4], l_i[4];
#pragma unroll
  for (int i = 0; i < 4; ++i) {
    Oacc[i] = (f32x4){0.f, 0.f, 0.f, 0.f};
    m_i[i] = -1e30f; l_i[i] = 0.f;
  }

  const int srow = tid >> 2, scol16 = (tid & 3) * 16;
  const int ntiles = j + 1;                // keys 0 .. q0+63

  // 2-deep prefetch: set A holds tile t (even), set B tile t (odd)
  uint4 kA0, kA1, vA0, vA1, kB0, kB1, vB0, vB1;
  {
    const uint4* kg = (const uint4*)&k[base + (size_t)srow * DH + scol16];
    kA0 = kg[0]; kA1 = kg[1];
    const uint4* vg = (const uint4*)&vt[base + (size_t)srow * S_LEN + scol16];
    vA0 = vg[0]; vA1 = vg[1];
  }
  if (ntiles > 1) {
    const uint4* kg = (const uint4*)&k[base + (size_t)(64 + srow) * DH + scol16];
    kB0 = kg[0]; kB1 = kg[1];
    const uint4* vg = (const uint4*)&vt[base + (size_t)srow * S_LEN + 64 + scol16];
    vB0 = vg[0]; vB1 = vg[1];
  }

  auto compute_tile = [&](int t) {
    // S = Q K^T   (t*64 <= q0 <= qm, so every tile is at least partly live)
    f32x4 S[4];
#pragma unroll
    for (int i = 0; i < 4; ++i) S[i] = (f32x4){0.f, 0.f, 0.f, 0.f};
#pragma unroll
    for (int kk = 0; kk < 2; ++kk) {
#pragma unroll
      for (int nt = 0; nt < 4; ++nt) {
        s16x8 kf = *(const s16x8*)&Kl[(nt * 16 + lm) * KVST + kk * 32 + lq * 8];
        S[nt] = __builtin_amdgcn_mfma_f32_16x16x32_bf16(aq[kk], kf, S[nt], 0, 0, 0);
      }
    }

    if (t * 64 + 63 > qm) {                // diagonal tile: causal mask
#pragma unroll
      for (int nt = 0; nt < 4; ++nt)
#pragma unroll
        for (int r = 0; r < 4; ++r) {
          const int keyg = t * 64 + nt * 16 + lm;
          const int qg = qm + lq * 4 + r;
          if (keyg > qg) S[nt][r] = -1e30f;
        }
    }

    // online softmax (exp2 units), T13 defer-max
#pragma unroll
    for (int r = 0; r < 4; ++r) {
      float rm = fmaxf(fmaxf(S[0][r], S[1][r]), fmaxf(S[2][r], S[3][r]));
      rm = fmaxf(rm, __shfl_xor(rm, 1));
      rm = fmaxf(rm, __shfl_xor(rm, 2));
      rm = fmaxf(rm, __shfl_xor(rm, 4));
      rm = fmaxf(rm, __shfl_xor(rm, 8));
      float mn = m_i[r];
      if (__any(rm > mn + DEFER_THR)) {    // wave-uniform rescale branch
        const float mnew = fmaxf(mn, rm);
        const float alpha = exp2f(mn - mnew);
        l_i[r] *= alpha;
#pragma unroll
        for (int nt = 0; nt < 4; ++nt) Oacc[nt][r] *= alpha;
        m_i[r] = mnew;
        mn = mnew;
      }
      float rs = 0.f;
#pragma unroll
      for (int nt = 0; nt < 4; ++nt) {
        float pv = exp2f(S[nt][r] - mn);
        S[nt][r] = pv;
        rs += pv;
      }
      rs += __shfl_xor(rs, 1);
      rs += __shfl_xor(rs, 2);
      rs += __shfl_xor(rs, 4);
      rs += __shfl_xor(rs, 8);
      l_i[r] += rs;
    }

    // P: C-layout regs -> per-wave LDS -> A-layout (same-wave: no barrier)
#pragma unroll
    for (int nt = 0; nt < 4; ++nt)
#pragma unroll
      for (int r = 0; r < 4; ++r)
        Pl[(wave * 16 + lq * 4 + r) * PST + nt * 16 + lm] = f2bf(S[nt][r]);

    // O += P V
#pragma unroll
    for (int kk = 0; kk < 2; ++kk) {
      s16x8 pa = *(const s16x8*)&Pl[(wave * 16 + lm) * PST + kk * 32 + lq * 8];
#pragma unroll
      for (int nt = 0; nt < 4; ++nt) {
        s16x8 vf = *(const s16x8*)&Vl[(nt * 16 + lm) * KVST + kk * 32 + lq * 8];
        Oacc[nt] = __builtin_amdgcn_mfma_f32_16x16x32_bf16(pa, vf, Oacc[nt], 0, 0, 0);
      }
    }
  };

  int t = 0;
  while (t < ntiles) {
    // even tile: stage from set A, refill A with tile t+2
    __syncthreads();
    *(uint4*)&Kl[srow * KVST + scol16] = kA0;
    *(uint4*)&Kl[srow * KVST + scol16 + 8] = kA1;
    *(uint4*)&Vl[srow * KVST + scol16] = vA0;
    *(uint4*)&Vl[srow * KVST + scol16 + 8] = vA1;
    if (t + 2 < ntiles) {
      const uint4* kg = (const uint4*)
          &k[base + (size_t)((t + 2) * 64 + srow) * DH + scol16];
      kA0 = kg[0]; kA1 = kg[1];
      const uint4* vg = (const uint4*)
          &vt[base + (size_t)srow * S_LEN + (t + 2) * 64 + scol16];
      vA0 = vg[0]; vA1 = vg[1];
    }
    __syncthreads();
    compute_tile(t);
    ++t;
    if (t >= ntiles) break;

    // odd tile: stage from set B, refill B with tile t+2
    __syncthreads();
    *(uint4*)&Kl[srow * KVST + scol16] = kB0;
    *(uint4*)&Kl[srow * KVST + scol16 + 8] = kB1;
    *(uint4*)&Vl[srow * KVST + scol16] = vB0;
    *(uint4*)&Vl[srow * KVST + scol16 + 8] = vB1;
    if (t + 2 < ntiles) {
      const uint4* kg = (const uint4*)
          &k[base + (size_t)((t + 2) * 64 + srow) * DH + scol16];
      kB0 = kg[0]; kB1 = kg[1];
      const uint4* vg = (const uint4*)
          &vt[base + (size_t)srow * S_LEN + (t + 2) * 64 + scol16];
      vB0 = vg[0]; vB1 = vg[1];
    }
    __syncthreads();
    compute_tile(t);
    ++t;
  }

  // normalize + store bf16 to aw (b, s, h*64+d)
  const int b = bh / NH, h = bh % NH;
#pragma unroll
  for (int nt = 0; nt < 4; ++nt)
#pragma unroll
    for (int r = 0; r < 4; ++r) {
      const int qg = qm + lq * 4 + r;
      const int dd = nt * 16 + lm;
      o[((size_t)(b * S_LEN + qg)) * DM + h * DH + dd] =
          f2bf(Oacc[nt][r] / l_i[r]);
    }
}

// ---------------------------------------------------------------------------
// Out-projection GEMM: C = aw @ wo^T. R2: 128x128 tile, BK=32, same structure
// as qkv (A is bf16, W f32->bf16 at staging). Grid 64x6.
// ---------------------------------------------------------------------------
__global__ __launch_bounds__(256) void out_proj_kernel(
    const u16* __restrict__ a, const float* __restrict__ wo,
    float* __restrict__ c)
{
  const int mTile = blockIdx.x * 128;
  const int nTile = blockIdx.y * 128;
  const int tid = threadIdx.x;
  const int wave = tid >> 6, lane = tid & 63;
  const int lm = lane & 15, lq = lane >> 4;
  const int wr = wave >> 1, wc = wave & 1;

  __shared__ u16 Al[128 * QST];
  __shared__ u16 Wl[128 * QST];

  f32x4 acc[4][4];
#pragma unroll
  for (int i = 0; i < 4; ++i)
#pragma unroll
    for (int jn = 0; jn < 4; ++jn) acc[i][jn] = (f32x4){0.f, 0.f, 0.f, 0.f};

  const int srow = tid >> 1, scol = (tid & 1) * 16;

  uint4 pa0, pa1;
  float4 pw0, pw1, pw2, pw3;
  {
    const uint4* ap = (const uint4*)&a[(size_t)(mTile + srow) * DM + scol];
    pa0 = ap[0]; pa1 = ap[1];
    const float4* wp = (const float4*)&wo[(size_t)(nTile + srow) * DM + scol];
    pw0 = wp[0]; pw1 = wp[1]; pw2 = wp[2]; pw3 = wp[3];
  }

  for (int k0 = 0; k0 < DM; k0 += 32) {
    __syncthreads();
    *(uint4*)&Al[srow * QST + scol] = pa0;
    *(uint4*)&Al[srow * QST + scol + 8] = pa1;
    *(s16x8*)&Wl[srow * QST + scol]     = pack_bf16x8(pw0, pw1);
    *(s16x8*)&Wl[srow * QST + scol + 8] = pack_bf16x8(pw2, pw3);
    if (k0 + 32 < DM) {
      const uint4* ap = (const uint4*)&a[(size_t)(mTile + srow) * DM + k0 + 32 + scol];
      pa0 = ap[0]; pa1 = ap[1];
      const float4* wp = (const float4*)&wo[(size_t)(nTile + srow) * DM + k0 + 32 + scol];
      pw0 = wp[0]; pw1 = wp[1]; pw2 = wp[2]; pw3 = wp[3];
    }
    __syncthreads();
    s16x8 af[4], bf[4];
#pragma unroll
    for (int mt = 0; mt < 4; ++mt)
      af[mt] = *(const s16x8*)&Al[(wr * 64 + mt * 16 + lm) * QST + lq * 8];
#pragma unroll
    for (int nt = 0; nt < 4; ++nt)
      bf[nt] = *(const s16x8*)&Wl[(wc * 64 + nt * 16 + lm) * QST + lq * 8];
#pragma unroll
    for (int mt = 0; mt < 4; ++mt)
#pragma unroll
      for (int nt = 0; nt < 4; ++nt)
        acc[mt][nt] = __builtin_amdgcn_mfma_f32_16x16x32_bf16(af[mt], bf[nt], acc[mt][nt], 0, 0, 0);
  }

#pragma unroll
  for (int mt = 0; mt < 4; ++mt)
#pragma unroll
    for (int nt = 0; nt < 4; ++nt)
#pragma unroll
      for (int r = 0; r < 4; ++r)
        c[(size_t)(mTile + wr * 64 + mt * 16 + lq * 4 + r) * DM +
          nTile + wc * 64 + nt * 16 + lm] = acc[mt][nt][r];
}

// ---------------------------------------------------------------------------
extern "C" void kernel_launch(void* const* d_in, const int* in_sizes, int n_in,
                              void* d_out, int out_size, void* d_ws, size_t ws_size,
                              hipStream_t stream) {
  const float* x  = (const float*)d_in[0];   // inputs: float32
  const float* wq = (const float*)d_in[1];
  const float* wk = (const float*)d_in[2];
  const float* wv = (const float*)d_in[3];
  const float* wo = (const float*)d_in[4];
  float* out = (float*)d_out;                // output: float32
  u16* ws  = (u16*)d_ws;

  const size_t QKV = (size_t)B_SZ * S_LEN * DM;  // 6291456 elems
  u16* qw = ws;                                  // ws: 4*QKV*2 + 512KB = 50.9MB
  u16* kw = ws + QKV;
  u16* vw = ws + 2 * QKV;                        // v TRANSPOSED (b,h,d,s)
  u16* aw = ws + 3 * QKV;                        // attention out, bf16 (b,s,dm)
  float2* tab = (float2*)(ws + 4 * QKV);         // 2048 x 32 cos/sin

  rope_table_kernel<<<dim3(S_LEN * 32 / 256), 256, 0, stream>>>(tab);
  qkv_rope_kernel<<<dim3(64, 6, 3), 256, 0, stream>>>(
      x, wq, wk, wv, tab, qw, kw, vw);
  attn_kernel<<<dim3((S_LEN / 64) * B_SZ * NH), 256, 0, stream>>>(qw, kw, vw, aw);
  out_proj_kernel<<<dim3(64, 6), 256, 0, stream>>>(aw, wo, out);
}

// Round 5
// 271.961 us; speedup vs baseline: 1.6002x; 1.1288x over previous
//
#include <hip/hip_runtime.h>
#include <hip/hip_bf16.h>

typedef float f32x4 __attribute__((ext_vector_type(4)));
typedef short s16x8 __attribute__((ext_vector_type(8)));
typedef unsigned short u16;
typedef unsigned int u32;
typedef __attribute__((address_space(1))) u32 gu32;
typedef __attribute__((address_space(3))) u32 lu32;

#define NH 12
#define DH 64
#define DM 768
#define S_LEN 2048
#define B_SZ 4

static __device__ __forceinline__ u16 f2bf(float f) {
  __hip_bfloat16 h = __float2bfloat16(f);
  return __builtin_bit_cast(u16, h);
}
static __device__ __forceinline__ s16x8 pack_bf16x8(float4 a, float4 b) {
  s16x8 r;
  r[0] = (short)f2bf(a.x); r[1] = (short)f2bf(a.y);
  r[2] = (short)f2bf(a.z); r[3] = (short)f2bf(a.w);
  r[4] = (short)f2bf(b.x); r[5] = (short)f2bf(b.y);
  r[6] = (short)f2bf(b.z); r[7] = (short)f2bf(b.w);
  return r;
}
// async global->LDS, 16B per lane; LDS dest = wave-uniform base + lane*16
static __device__ __forceinline__ void glds16(const u16* g, u16* l) {
  __builtin_amdgcn_global_load_lds((const gu32*)g, (lu32*)l, 16, 0, 0);
}

// ---------------------------------------------------------------------------
// RoPE cos/sin table: tab[pos*32+i] = {cos,sin}(pos * 10000^(-2i/64)).
// ---------------------------------------------------------------------------
__global__ __launch_bounds__(256) void rope_table_kernel(float2* __restrict__ tab) {
  const int idx = blockIdx.x * 256 + threadIdx.x;   // 0..65535 exact
  const int sl = idx >> 5, i = idx & 31;
  const float inv_freq = exp2f((float)(2 * i) * (-13.287712379549449f / 64.0f));
  float s, c;
  sincosf((float)sl * inv_freq, &s, &c);
  tab[idx] = make_float2(c, s);
}

// ---------------------------------------------------------------------------
// R4: one-time f32->bf16 conversion of x and all 4 weight matrices.
// Same RNE rounding as before (f2bf), so results are bit-identical.
// x: 6291456 elems (786432 units of 8); each w: 589824 (73728 units).
// ---------------------------------------------------------------------------
__global__ __launch_bounds__(256) void convert_bf16_kernel(
    const float* __restrict__ x, const float* __restrict__ wq,
    const float* __restrict__ wk, const float* __restrict__ wv,
    const float* __restrict__ wo,
    u16* __restrict__ xb, u16* __restrict__ wqb, u16* __restrict__ wkb,
    u16* __restrict__ wvb, u16* __restrict__ wob)
{
  const int u = blockIdx.x * 256 + threadIdx.x;   // 0..1081343 exact
  const float* src; u16* dst; int off;
  if (u < 786432) {
    src = x; dst = xb; off = u;
  } else {
    const int wu = u - 786432;
    const int w = wu / 73728, o = wu - w * 73728;
    src = (w == 0) ? wq : (w == 1) ? wk : (w == 2) ? wv : wo;
    dst = (w == 0) ? wqb : (w == 1) ? wkb : (w == 2) ? wvb : wob;
    off = o;
  }
  const float4* s = (const float4*)(src + (size_t)off * 8);
  float4 a = s[0], b = s[1];
  *(s16x8*)(dst + (size_t)off * 8) = pack_bf16x8(a, b);
}

// ---------------------------------------------------------------------------
// QKV projection + RoPE. R4: m97 structure — bf16 inputs, global_load_lds
// width-16 staging into LINEAR [128][32] LDS (fragment reads land at the
// b128 8-words/bank floor), 128x128 tile, BK=32, zero staging VALU.
// V epilogue routed through LDS so stores are 64B-coalesced (was 2B scatter
// at 4KB stride).
// ---------------------------------------------------------------------------
#define QSCALE 0.18033688011112042f   // 0.125 * log2(e)

__global__ __launch_bounds__(256) void qkv_rope_kernel(
    const u16* __restrict__ xb, const u16* __restrict__ wqb,
    const u16* __restrict__ wkb, const u16* __restrict__ wvb,
    const float2* __restrict__ tab,
    u16* __restrict__ qo, u16* __restrict__ ko, u16* __restrict__ vo)
{
  const int z = blockIdx.z;                 // 0=q 1=k 2=v
  const u16* Wp = (z == 0) ? wqb : (z == 1) ? wkb : wvb;
  u16* Op = (z == 0) ? qo : (z == 1) ? ko : vo;
  const int mTile = blockIdx.x * 128;
  const int nTile = blockIdx.y * 128;
  const int tid = threadIdx.x;
  const int wave = tid >> 6, lane = tid & 63;
  const int lm = lane & 15, lq = lane >> 4;
  const int wr = wave >> 1, wc = wave & 1;  // 2x2 wave grid over 128x128

  __shared__ u16 Al[128 * 32];
  __shared__ u16 Bl[128 * 32];
  __shared__ u16 Tl[64 * 136];              // v-transpose staging

  f32x4 acc[4][4];
#pragma unroll
  for (int i = 0; i < 4; ++i)
#pragma unroll
    for (int jn = 0; jn < 4; ++jn) acc[i][jn] = (f32x4){0.f, 0.f, 0.f, 0.f};

  // staging: wave w covers rows w*16+(lane>>2) (+64 for chunk 1), 16B cols
  const int srA = wave * 16 + (lane >> 2);
  const int scA = (lane & 3) * 8;           // u16 col offset

  for (int k0 = 0; k0 < DM; k0 += 32) {
    __syncthreads();
    glds16(&xb[(size_t)(mTile + srA) * DM + k0 + scA],      &Al[(wave * 16) * 32]);
    glds16(&xb[(size_t)(mTile + 64 + srA) * DM + k0 + scA], &Al[(64 + wave * 16) * 32]);
    glds16(&Wp[(size_t)(nTile + srA) * DM + k0 + scA],      &Bl[(wave * 16) * 32]);
    glds16(&Wp[(size_t)(nTile + 64 + srA) * DM + k0 + scA], &Bl[(64 + wave * 16) * 32]);
    __syncthreads();
    s16x8 af[4], bf[4];
#pragma unroll
    for (int mt = 0; mt < 4; ++mt)
      af[mt] = *(const s16x8*)&Al[(wr * 64 + mt * 16 + lm) * 32 + lq * 8];
#pragma unroll
    for (int nt = 0; nt < 4; ++nt)
      bf[nt] = *(const s16x8*)&Bl[(wc * 64 + nt * 16 + lm) * 32 + lq * 8];
#pragma unroll
    for (int mt = 0; mt < 4; ++mt)
#pragma unroll
      for (int nt = 0; nt < 4; ++nt)
        acc[mt][nt] = __builtin_amdgcn_mfma_f32_16x16x32_bf16(af[mt], bf[nt], acc[mt][nt], 0, 0, 0);
  }

  if (z < 2) {
    // C/D layout (m89): col = lane&15, row = (lane>>4)*4 + r; RoPE partner lane^1
#pragma unroll
    for (int mt = 0; mt < 4; ++mt)
#pragma unroll
      for (int nt = 0; nt < 4; ++nt)
#pragma unroll
        for (int r = 0; r < 4; ++r) {
          float val = acc[mt][nt][r];
          float partner = __shfl_xor(val, 1);
          const int mI = mTile + wr * 64 + mt * 16 + lq * 4 + r;  // token
          const int nI = nTile + wc * 64 + nt * 16 + lm;          // feature
          const int b = mI >> 11, sl2 = mI & (S_LEN - 1);
          const int h = nI >> 6, dd = nI & 63;
          const float2 cs = tab[sl2 * 32 + (dd >> 1)];
          float res = val * cs.x + partner * ((dd & 1) ? cs.y : -cs.y);
          if (z == 0) res *= QSCALE;
          Op[(((size_t)(b * NH + h)) * S_LEN + sl2) * DH + dd] = f2bf(res);
        }
  } else {
    // v transposed (b,h,d,s): stage 128x64 feature-half in LDS, store
    // 64B-contiguous token runs (was per-thread 2B scatter at 4KB stride).
    const int b = mTile >> 11;               // block-uniform (128 | 2048)
    const int sbase = mTile & (S_LEN - 1);
#pragma unroll
    for (int half = 0; half < 2; ++half) {
      __syncthreads();
      if (wc == half) {
#pragma unroll
        for (int mt = 0; mt < 4; ++mt)
#pragma unroll
          for (int nt = 0; nt < 4; ++nt) {
            ushort4 pk;
            pk.x = f2bf(acc[mt][nt][0]);
            pk.y = f2bf(acc[mt][nt][1]);
            pk.z = f2bf(acc[mt][nt][2]);
            pk.w = f2bf(acc[mt][nt][3]);
            *(ushort4*)&Tl[(nt * 16 + lm) * 136 + wr * 64 + mt * 16 + lq * 4] = pk;
          }
      }
      __syncthreads();
      const int f = tid >> 2, cch = (tid & 3) * 32;  // feature, token chunk
      const int nI = nTile + half * 64 + f;
      const int h = nI >> 6, dd = nI & 63;
      u16* vrow = &Op[(((size_t)(b * NH + h)) * DH + dd) * S_LEN + sbase + cch];
      const uint4* ts = (const uint4*)&Tl[f * 136 + cch];
      uint4 t0 = ts[0], t1 = ts[1], t2 = ts[2], t3 = ts[3];
      ((uint4*)vrow)[0] = t0; ((uint4*)vrow)[1] = t1;
      ((uint4*)vrow)[2] = t2; ((uint4*)vrow)[3] = t3;
    }
  }
}

// ---------------------------------------------------------------------------
// MFMA flash attention — UNCHANGED from R3 (clean A/B; counters frozen).
// ---------------------------------------------------------------------------
#define KVST 72
#define PST 76
#define DEFER_THR 8.0f

__global__ __launch_bounds__(256) void attn_kernel(
    const u16* __restrict__ q, const u16* __restrict__ k,
    const u16* __restrict__ vt, u16* __restrict__ o)
{
  const int p = blockIdx.x;
  const int bh = p % 48;
  const int j = (S_LEN / 64 - 1) - p / 48;              // heavy tiles first
  const size_t base = (size_t)bh * S_LEN * DH;          // same for (s,d)/(d,s)
  const int tid = threadIdx.x;
  const int wave = tid >> 6, lane = tid & 63;
  const int lm = lane & 15, lq = lane >> 4;

  __shared__ u16 Kl[64 * KVST];            // [key][d]
  __shared__ u16 Vl[64 * KVST];            // [d][key]
  __shared__ u16 Pl[64 * PST];             // per-wave 16 q-rows x 64 keys

  const int q0 = j * 64;
  const int qm = q0 + wave * 16;           // this wave's 16 q-rows

  s16x8 aq[2];
#pragma unroll
  for (int kk = 0; kk < 2; ++kk)
    aq[kk] = *(const s16x8*)&q[base + (size_t)(qm + lm) * DH + kk * 32 + lq * 8];

  f32x4 Oacc[4];
  float m_i[4], l_i[4];
#pragma unroll
  for (int i = 0; i < 4; ++i) {
    Oacc[i] = (f32x4){0.f, 0.f, 0.f, 0.f};
    m_i[i] = -1e30f; l_i[i] = 0.f;
  }

  const int srow = tid >> 2, scol16 = (tid & 3) * 16;
  const int ntiles = j + 1;                // keys 0 .. q0+63

  // 2-deep prefetch: set A holds tile t (even), set B tile t (odd)
  uint4 kA0, kA1, vA0, vA1, kB0, kB1, vB0, vB1;
  {
    const uint4* kg = (const uint4*)&k[base + (size_t)srow * DH + scol16];
    kA0 = kg[0]; kA1 = kg[1];
    const uint4* vg = (const uint4*)&vt[base + (size_t)srow * S_LEN + scol16];
    vA0 = vg[0]; vA1 = vg[1];
  }
  if (ntiles > 1) {
    const uint4* kg = (const uint4*)&k[base + (size_t)(64 + srow) * DH + scol16];
    kB0 = kg[0]; kB1 = kg[1];
    const uint4* vg = (const uint4*)&vt[base + (size_t)srow * S_LEN + 64 + scol16];
    vB0 = vg[0]; vB1 = vg[1];
  }

  auto compute_tile = [&](int t) {
    f32x4 S[4];
#pragma unroll
    for (int i = 0; i < 4; ++i) S[i] = (f32x4){0.f, 0.f, 0.f, 0.f};
#pragma unroll
    for (int kk = 0; kk < 2; ++kk) {
#pragma unroll
      for (int nt = 0; nt < 4; ++nt) {
        s16x8 kf = *(const s16x8*)&Kl[(nt * 16 + lm) * KVST + kk * 32 + lq * 8];
        S[nt] = __builtin_amdgcn_mfma_f32_16x16x32_bf16(aq[kk], kf, S[nt], 0, 0, 0);
      }
    }

    if (t * 64 + 63 > qm) {                // diagonal tile: causal mask
#pragma unroll
      for (int nt = 0; nt < 4; ++nt)
#pragma unroll
        for (int r = 0; r < 4; ++r) {
          const int keyg = t * 64 + nt * 16 + lm;
          const int qg = qm + lq * 4 + r;
          if (keyg > qg) S[nt][r] = -1e30f;
        }
    }

    // online softmax (exp2 units), T13 defer-max
#pragma unroll
    for (int r = 0; r < 4; ++r) {
      float rm = fmaxf(fmaxf(S[0][r], S[1][r]), fmaxf(S[2][r], S[3][r]));
      rm = fmaxf(rm, __shfl_xor(rm, 1));
      rm = fmaxf(rm, __shfl_xor(rm, 2));
      rm = fmaxf(rm, __shfl_xor(rm, 4));
      rm = fmaxf(rm, __shfl_xor(rm, 8));
      float mn = m_i[r];
      if (__any(rm > mn + DEFER_THR)) {    // wave-uniform rescale branch
        const float mnew = fmaxf(mn, rm);
        const float alpha = exp2f(mn - mnew);
        l_i[r] *= alpha;
#pragma unroll
        for (int nt = 0; nt < 4; ++nt) Oacc[nt][r] *= alpha;
        m_i[r] = mnew;
        mn = mnew;
      }
      float rs = 0.f;
#pragma unroll
      for (int nt = 0; nt < 4; ++nt) {
        float pv = exp2f(S[nt][r] - mn);
        S[nt][r] = pv;
        rs += pv;
      }
      rs += __shfl_xor(rs, 1);
      rs += __shfl_xor(rs, 2);
      rs += __shfl_xor(rs, 4);
      rs += __shfl_xor(rs, 8);
      l_i[r] += rs;
    }

    // P: C-layout regs -> per-wave LDS -> A-layout (same-wave: no barrier)
#pragma unroll
    for (int nt = 0; nt < 4; ++nt)
#pragma unroll
      for (int r = 0; r < 4; ++r)
        Pl[(wave * 16 + lq * 4 + r) * PST + nt * 16 + lm] = f2bf(S[nt][r]);

    // O += P V
#pragma unroll
    for (int kk = 0; kk < 2; ++kk) {
      s16x8 pa = *(const s16x8*)&Pl[(wave * 16 + lm) * PST + kk * 32 + lq * 8];
#pragma unroll
      for (int nt = 0; nt < 4; ++nt) {
        s16x8 vf = *(const s16x8*)&Vl[(nt * 16 + lm) * KVST + kk * 32 + lq * 8];
        Oacc[nt] = __builtin_amdgcn_mfma_f32_16x16x32_bf16(pa, vf, Oacc[nt], 0, 0, 0);
      }
    }
  };

  int t = 0;
  while (t < ntiles) {
    __syncthreads();
    *(uint4*)&Kl[srow * KVST + scol16] = kA0;
    *(uint4*)&Kl[srow * KVST + scol16 + 8] = kA1;
    *(uint4*)&Vl[srow * KVST + scol16] = vA0;
    *(uint4*)&Vl[srow * KVST + scol16 + 8] = vA1;
    if (t + 2 < ntiles) {
      const uint4* kg = (const uint4*)
          &k[base + (size_t)((t + 2) * 64 + srow) * DH + scol16];
      kA0 = kg[0]; kA1 = kg[1];
      const uint4* vg = (const uint4*)
          &vt[base + (size_t)srow * S_LEN + (t + 2) * 64 + scol16];
      vA0 = vg[0]; vA1 = vg[1];
    }
    __syncthreads();
    compute_tile(t);
    ++t;
    if (t >= ntiles) break;

    __syncthreads();
    *(uint4*)&Kl[srow * KVST + scol16] = kB0;
    *(uint4*)&Kl[srow * KVST + scol16 + 8] = kB1;
    *(uint4*)&Vl[srow * KVST + scol16] = vB0;
    *(uint4*)&Vl[srow * KVST + scol16 + 8] = vB1;
    if (t + 2 < ntiles) {
      const uint4* kg = (const uint4*)
          &k[base + (size_t)((t + 2) * 64 + srow) * DH + scol16];
      kB0 = kg[0]; kB1 = kg[1];
      const uint4* vg = (const uint4*)
          &vt[base + (size_t)srow * S_LEN + (t + 2) * 64 + scol16];
      vB0 = vg[0]; vB1 = vg[1];
    }
    __syncthreads();
    compute_tile(t);
    ++t;
  }

  // normalize + store bf16 to aw (b, s, h*64+d)
  const int b = bh / NH, h = bh % NH;
#pragma unroll
  for (int nt = 0; nt < 4; ++nt)
#pragma unroll
    for (int r = 0; r < 4; ++r) {
      const int qg = qm + lq * 4 + r;
      const int dd = nt * 16 + lm;
      o[((size_t)(b * S_LEN + qg)) * DM + h * DH + dd] =
          f2bf(Oacc[nt][r] / l_i[r]);
    }
}

// ---------------------------------------------------------------------------
// Out-projection GEMM: C = aw @ wo^T. R4: m97 structure, both inputs bf16,
// global_load_lds staging, linear LDS.
// ---------------------------------------------------------------------------
__global__ __launch_bounds__(256) void out_proj_kernel(
    const u16* __restrict__ a, const u16* __restrict__ wob,
    float* __restrict__ c)
{
  const int mTile = blockIdx.x * 128;
  const int nTile = blockIdx.y * 128;
  const int tid = threadIdx.x;
  const int wave = tid >> 6, lane = tid & 63;
  const int lm = lane & 15, lq = lane >> 4;
  const int wr = wave >> 1, wc = wave & 1;

  __shared__ u16 Al[128 * 32];
  __shared__ u16 Bl[128 * 32];

  f32x4 acc[4][4];
#pragma unroll
  for (int i = 0; i < 4; ++i)
#pragma unroll
    for (int jn = 0; jn < 4; ++jn) acc[i][jn] = (f32x4){0.f, 0.f, 0.f, 0.f};

  const int srA = wave * 16 + (lane >> 2);
  const int scA = (lane & 3) * 8;

  for (int k0 = 0; k0 < DM; k0 += 32) {
    __syncthreads();
    glds16(&a[(size_t)(mTile + srA) * DM + k0 + scA],        &Al[(wave * 16) * 32]);
    glds16(&a[(size_t)(mTile + 64 + srA) * DM + k0 + scA],   &Al[(64 + wave * 16) * 32]);
    glds16(&wob[(size_t)(nTile + srA) * DM + k0 + scA],      &Bl[(wave * 16) * 32]);
    glds16(&wob[(size_t)(nTile + 64 + srA) * DM + k0 + scA], &Bl[(64 + wave * 16) * 32]);
    __syncthreads();
    s16x8 af[4], bf[4];
#pragma unroll
    for (int mt = 0; mt < 4; ++mt)
      af[mt] = *(const s16x8*)&Al[(wr * 64 + mt * 16 + lm) * 32 + lq * 8];
#pragma unroll
    for (int nt = 0; nt < 4; ++nt)
      bf[nt] = *(const s16x8*)&Bl[(wc * 64 + nt * 16 + lm) * 32 + lq * 8];
#pragma unroll
    for (int mt = 0; mt < 4; ++mt)
#pragma unroll
      for (int nt = 0; nt < 4; ++nt)
        acc[mt][nt] = __builtin_amdgcn_mfma_f32_16x16x32_bf16(af[mt], bf[nt], acc[mt][nt], 0, 0, 0);
  }

#pragma unroll
  for (int mt = 0; mt < 4; ++mt)
#pragma unroll
    for (int nt = 0; nt < 4; ++nt)
#pragma unroll
      for (int r = 0; r < 4; ++r)
        c[(size_t)(mTile + wr * 64 + mt * 16 + lq * 4 + r) * DM +
          nTile + wc * 64 + nt * 16 + lm] = acc[mt][nt][r];
}

// ---------------------------------------------------------------------------
extern "C" void kernel_launch(void* const* d_in, const int* in_sizes, int n_in,
                              void* d_out, int out_size, void* d_ws, size_t ws_size,
                              hipStream_t stream) {
  const float* x  = (const float*)d_in[0];   // inputs: float32
  const float* wq = (const float*)d_in[1];
  const float* wk = (const float*)d_in[2];
  const float* wv = (const float*)d_in[3];
  const float* wo = (const float*)d_in[4];
  float* out = (float*)d_out;                // output: float32
  u16* ws  = (u16*)d_ws;

  const size_t QKV = (size_t)B_SZ * S_LEN * DM;  // 6291456 elems
  u16* qw = ws;
  u16* kw = ws + QKV;
  u16* vw = ws + 2 * QKV;                        // v TRANSPOSED (b,h,d,s)
  u16* aw = ws + 3 * QKV;                        // xbf during qkv; attn out after
  float2* tab = (float2*)(ws + 4 * QKV);         // 2048 x 32 cos/sin (512KB)
  u16* wqb = ws + 4 * QKV + 262144;              // bf16 weights (1.18MB each)
  u16* wkb = wqb + 589824;
  u16* wvb = wkb + 589824;
  u16* wob = wvb + 589824;                       // total ws: ~55.6MB

  u16* xbf = aw;                                 // region shared with aw

  rope_table_kernel<<<dim3(S_LEN * 32 / 256), 256, 0, stream>>>(tab);
  convert_bf16_kernel<<<dim3(4224), 256, 0, stream>>>(
      x, wq, wk, wv, wo, xbf, wqb, wkb, wvb, wob);
  qkv_rope_kernel<<<dim3(64, 6, 3), 256, 0, stream>>>(
      xbf, wqb, wkb, wvb, tab, qw, kw, vw);
  attn_kernel<<<dim3((S_LEN / 64) * B_SZ * NH), 256, 0, stream>>>(qw, kw, vw, aw);
  out_proj_kernel<<<dim3(64, 6), 256, 0, stream>>>(aw, wob, out);
}